// Round 5
// baseline (255.002 us; speedup 1.0000x reference)
//
#include <hip/hip_runtime.h>
#include <cstdint>
#include <cstddef>

#define NN 8192
#define FI 128
#define FO 128
#define NCH 4
// Half-buffer: [2 channels][32 rows][512 k] bf16 = 64 KB. 32 halves:
// half h covers channels {(h&1)*2, (h&1)*2+1}, k-range [(h>>1)*512, +512).

typedef __attribute__((ext_vector_type(8))) __bf16 bf16x8;
typedef __attribute__((ext_vector_type(8))) short short8;
typedef __attribute__((ext_vector_type(4))) float f32x4;

static __device__ __forceinline__ f32x4 mfma16(bf16x8 a, bf16x8 b, f32x4 c) {
  return __builtin_amdgcn_mfma_f32_16x16x32_bf16(a, b, c, 0, 0, 0);
}

static __device__ __forceinline__ unsigned short f2bfu(float f) {
  union { __bf16 h; unsigned short u; } cv;
  cv.h = (__bf16)f;
  return cv.u;
}

static __device__ __forceinline__ unsigned int pack2(float a, float b) {
  return (unsigned int)f2bfu(a) | ((unsigned int)f2bfu(b) << 16);
}

static __device__ __forceinline__ bf16x8 cvt8v(f32x4 a, f32x4 b) {
  bf16x8 v;
  v[0] = (__bf16)a[0]; v[1] = (__bf16)a[1]; v[2] = (__bf16)a[2]; v[3] = (__bf16)a[3];
  v[4] = (__bf16)b[0]; v[5] = (__bf16)b[1]; v[6] = (__bf16)b[2]; v[7] = (__bf16)b[3];
  return v;
}

// ---------------------------------------------------------------------------
// Combined prep: blocks 0..511 pack X into PX (B-frag order); blocks 512..551
// pack the 5 weight matrices (adj_W c=0..3, W as c=4) into PW.
// B-frag: frag g, lane l holds M[kk*32 + (l>>4)*8 + j][nt*16 + (l&15)].
// ---------------------------------------------------------------------------
__global__ void gcs_prep(const float* __restrict__ X, const float* __restrict__ AW,
                         const float* __restrict__ W,
                         unsigned short* __restrict__ PX, unsigned short* __restrict__ PW) {
  if (blockIdx.x < 512) {
    int gid = blockIdx.x * 256 + threadIdx.x;   // 131072 threads
    int l   = gid & 63;
    int g   = gid >> 6;                          // 0..2047
    int kk  = g & 255;
    int nt  = g >> 8;
    int col = nt * 16 + (l & 15);
    int k0  = kk * 32 + (l >> 4) * 8;
    unsigned int w[4];
#pragma unroll
    for (int p = 0; p < 4; ++p)
      w[p] = pack2(X[(size_t)(k0 + 2 * p) * FI + col], X[(size_t)(k0 + 2 * p + 1) * FI + col]);
    ((uint4*)PX)[g * 64 + l] = make_uint4(w[0], w[1], w[2], w[3]);
  } else {
    int gid = (blockIdx.x - 512) * 256 + threadIdx.x;  // 10240 threads
    int l   = gid & 63;
    int g   = gid >> 6;                          // 0..159  (= c*32 + ot*4 + ks)
    int ks  = g & 3;
    int ot  = (g >> 2) & 7;
    int c   = g >> 5;                            // 0..4 ; 4 == W
    const float* base = (c < 4) ? (AW + (size_t)c * FI * FO) : W;
    int col = ot * 16 + (l & 15);
    int k0  = ks * 32 + (l >> 4) * 8;
    unsigned int w[4];
#pragma unroll
    for (int p = 0; p < 4; ++p)
      w[p] = pack2(base[(k0 + 2 * p) * FO + col], base[(k0 + 2 * p + 1) * FO + col]);
    ((uint4*)PW)[g * 64 + l] = make_uint4(w[0], w[1], w[2], w[3]);
  }
}

// ---------------------------------------------------------------------------
// Main (fully fused, 1 block/CU, 8 waves). Per half: each wave loads 8 rows x
// 2 KB CONTIGUOUS (2 back-to-back 1KB wave-bursts per row) -> 4096 streams
// device-wide. Double-buffered LDS, loads issued one compute-phase ahead, one
// barrier per half. Even halves: ch{0,1}; odd: ch{2,3} (compile-time parity).
// Epilogue: per-channel relu(AX_c @ adjW_c) + X@W (bf16 MFMA) + b, relu, store.
// ---------------------------------------------------------------------------
__global__ void __launch_bounds__(512, 2)
gcs_main(const float* __restrict__ adjs, const unsigned short* __restrict__ PX,
         const unsigned short* __restrict__ PW, const float* __restrict__ X,
         const float* __restrict__ b, float* __restrict__ out) {
  const int rt  = blockIdx.x;      // 0..255 row tile
  const int tid = threadIdx.x;
  const int w   = tid >> 6;        // wave 0..7 (owns col-tile w)
  const int l   = tid & 63;
  const int lr  = l & 15;
  const int lk  = l >> 4;

  // 2 half-buffers [2cc][32r][512k] bf16; byte = cc*32768 + ((r*1024+k*2)^((r&7)<<4))
  __shared__ unsigned short buf[2][2 * 32 * 512];   // 128 KB

  f32x4 acc[NCH][2] = {};     // all indices compile-time
  f32x4 pf[16];               // 8 rows x 2 KB per wave, statically indexed

#define LOADH(par, kq)                                                         \
  _Pragma("unroll") for (int j = 0; j < 8; ++j) {                              \
    int p = w * 8 + j; int cc = p >> 5; int r = p & 31;                        \
    const float* src = adjs + (size_t)((par) * 2 + cc) * NN * NN +             \
        (size_t)(rt * 32 + r) * NN + (size_t)(kq) * 512 + l * 4;               \
    pf[j * 2 + 0] = __builtin_nontemporal_load((const f32x4*)src);             \
    pf[j * 2 + 1] = __builtin_nontemporal_load((const f32x4*)(src + 256));     \
  }

#define CVTSTORE(dst)                                                          \
  _Pragma("unroll") for (int j = 0; j < 8; ++j) {                              \
    int p = w * 8 + j; int cc = p >> 5; int r = p & 31;                        \
    _Pragma("unroll") for (int q = 0; q < 2; ++q) {                            \
      unsigned int w0 = pack2(pf[j * 2 + q][0], pf[j * 2 + q][1]);             \
      unsigned int w1 = pack2(pf[j * 2 + q][2], pf[j * 2 + q][3]);             \
      int byte = cc * 32768 + ((r * 1024 + q * 512 + l * 8) ^ ((r & 7) << 4)); \
      *(uint2*)((char*)(dst) + byte) = make_uint2(w0, w1);                     \
    }                                                                          \
  }

#define COMPUTE(bufp, kq, c0, c1)                                              \
  _Pragma("unroll") for (int s = 0; s < 16; ++s) {                             \
    bf16x8 B = *(const bf16x8*)((const char*)PX +                              \
        ((size_t)(w * 256 + (kq) * 16 + s) * 64 + l) * 16);                    \
    _Pragma("unroll") for (int m = 0; m < 2; ++m) {                            \
      int r = m * 16 + lr;                                                     \
      int byt = (r * 1024 + s * 64 + lk * 16) ^ ((r & 7) << 4);                \
      bf16x8 A0 = __builtin_bit_cast(bf16x8,                                   \
          *(const short8*)((const char*)(bufp) + byt));                        \
      bf16x8 A1 = __builtin_bit_cast(bf16x8,                                   \
          *(const short8*)((const char*)(bufp) + 32768 + byt));                \
      acc[c0][m] = mfma16(A0, B, acc[c0][m]);                                  \
      acc[c1][m] = mfma16(A1, B, acc[c1][m]);                                  \
    }                                                                          \
  }

  // ---- prologue ----
  LOADH(0, 0);
  CVTSTORE(buf[0]);
  LOADH(1, 0);
  __syncthreads();

  // ---- 16 iterations, 2 halves each ----
  for (int hh = 0; hh < 16; ++hh) {
    COMPUTE(buf[0], hh, 0, 1);
    CVTSTORE(buf[1]);                     // pf = odd half hh
    if (hh < 15) LOADH(0, hh + 1);
    __syncthreads();

    COMPUTE(buf[1], hh, 2, 3);
    if (hh < 15) {
      CVTSTORE(buf[0]);                   // pf = even half hh+1
      LOADH(1, hh + 1);
    }
    __syncthreads();
  }

  // ---- epilogue: per channel relu(AX_c @ adjW_c), summed in regs ----
  char* AXs = (char*)buf;                 // 8 KB reshape scratch (aliases buf)
  f32x4 osum0 = {}, osum1 = {};
#pragma unroll
  for (int c = 0; c < NCH; ++c) {
    __syncthreads();
#pragma unroll
    for (int m = 0; m < 2; ++m) {
#pragma unroll
      for (int rr = 0; rr < 4; ++rr) {
        int row = m * 16 + lk * 4 + rr;
        int col = w * 16 + lr;
        int byte = (row * 256 + col * 2) ^ ((row & 7) << 4);
        *(unsigned short*)(AXs + byte) = f2bfu(acc[c][m][rr]);
      }
    }
    __syncthreads();
    f32x4 p0 = {}, p1 = {};
#pragma unroll
    for (int ks = 0; ks < 4; ++ks) {
      int kb = ks * 64 + lk * 16;
      int r0 = lr, r1 = 16 + lr;
      int b0 = (r0 * 256 + kb) ^ ((r0 & 7) << 4);
      int b1 = (r1 * 256 + kb) ^ ((r1 & 7) << 4);
      bf16x8 a0 = __builtin_bit_cast(bf16x8, *(const short8*)(AXs + b0));
      bf16x8 a1 = __builtin_bit_cast(bf16x8, *(const short8*)(AXs + b1));
      bf16x8 bw = *(const bf16x8*)((const char*)PW +
          ((size_t)(c * 32 + w * 4 + ks) * 64 + l) * 16);
      p0 = mfma16(a0, bw, p0);
      p1 = mfma16(a1, bw, p1);
    }
#pragma unroll
    for (int rr = 0; rr < 4; ++rr) {
      osum0[rr] += fmaxf(p0[rr], 0.0f);
      osum1[rr] += fmaxf(p1[rr], 0.0f);
    }
  }

  // ---- fused x_part = X@W via MFMA (X rows direct from L3-resident X) ----
  f32x4 xp0 = {}, xp1 = {};
#pragma unroll
  for (int ks = 0; ks < 4; ++ks) {
    bf16x8 bw = *(const bf16x8*)((const char*)PW +
        ((size_t)(128 + w * 4 + ks) * 64 + l) * 16);
#pragma unroll
    for (int m = 0; m < 2; ++m) {
      int row_g = rt * 32 + m * 16 + lr;
      const float* px = X + (size_t)row_g * FI + ks * 32 + lk * 8;
      f32x4 xa = *(const f32x4*)px;
      f32x4 xb = *(const f32x4*)(px + 4);
      bf16x8 a = cvt8v(xa, xb);
      if (m == 0) xp0 = mfma16(a, bw, xp0);
      else        xp1 = mfma16(a, bw, xp1);
    }
  }

  // ---- total = adj_part + x_part + b ; relu ; store ----
  float bias = b[w * 16 + lr];
#pragma unroll
  for (int m = 0; m < 2; ++m) {
#pragma unroll
    for (int rr = 0; rr < 4; ++rr) {
      int row = rt * 32 + m * 16 + lk * 4 + rr;
      int col = w * 16 + lr;
      float s = (m == 0 ? osum0[rr] : osum1[rr]) +
                (m == 0 ? xp0[rr]   : xp1[rr]) + bias;
      out[(size_t)row * FO + col] = fmaxf(s, 0.0f);
    }
  }
#undef LOADH
#undef CVTSTORE
#undef COMPUTE
}

extern "C" void kernel_launch(void* const* d_in, const int* in_sizes, int n_in,
                              void* d_out, int out_size, void* d_ws, size_t ws_size,
                              hipStream_t stream) {
  const float* X    = (const float*)d_in[0];   // [8192][128]
  const float* adjs = (const float*)d_in[1];   // [4][8192][8192]
  const float* W    = (const float*)d_in[2];   // [128][128]
  const float* AW   = (const float*)d_in[3];   // [4][128][128]
  const float* b    = (const float*)d_in[4];   // [128]
  float* out = (float*)d_out;

  char* ws = (char*)d_ws;
  unsigned short* PX = (unsigned short*)ws;                 // 2 MB
  unsigned short* PW = (unsigned short*)(ws + (2u << 20));  // 160 KB (5 matrices)

  hipLaunchKernelGGL(gcs_prep, dim3(552), dim3(256), 0, stream, X, AW, W, PX, PW);
  hipLaunchKernelGGL(gcs_main, dim3(256), dim3(512), 0, stream, adjs, PX, PW, X, b, out);
}

// Round 6
// 219.720 us; speedup vs baseline: 1.1606x; 1.1606x over previous
//
#include <hip/hip_runtime.h>
#include <cstdint>
#include <cstddef>

#define NN 8192
#define FI 128
#define FO 128
#define NCH 4
#define HK 256              // k-floats per half-buffer
#define NH (NN / HK)        // 32 halves

typedef __attribute__((ext_vector_type(8))) __bf16 bf16x8;
typedef __attribute__((ext_vector_type(8))) short short8;
typedef __attribute__((ext_vector_type(4))) float f32x4;

static __device__ __forceinline__ f32x4 mfma16(bf16x8 a, bf16x8 b, f32x4 c) {
  return __builtin_amdgcn_mfma_f32_16x16x32_bf16(a, b, c, 0, 0, 0);
}

static __device__ __forceinline__ unsigned short f2bfu(float f) {
  union { __bf16 h; unsigned short u; } cv;
  cv.h = (__bf16)f;
  return cv.u;
}

static __device__ __forceinline__ unsigned int pack2(float a, float b) {
  return (unsigned int)f2bfu(a) | ((unsigned int)f2bfu(b) << 16);
}

static __device__ __forceinline__ bf16x8 cvt8v(f32x4 a, f32x4 b) {
  bf16x8 v;
  v[0] = (__bf16)a[0]; v[1] = (__bf16)a[1]; v[2] = (__bf16)a[2]; v[3] = (__bf16)a[3];
  v[4] = (__bf16)b[0]; v[5] = (__bf16)b[1]; v[6] = (__bf16)b[2]; v[7] = (__bf16)b[3];
  return v;
}

// ---------------------------------------------------------------------------
// Prep: blocks 0..511 pack X -> PX (B-frag order); blocks 512..551 pack the
// 5 weight matrices (adj_W c=0..3, W as c=4) -> PW.
// B-frag: frag g, lane l holds M[kk*32 + (l>>4)*8 + j][nt*16 + (l&15)].
// ---------------------------------------------------------------------------
__global__ void gcs_prep(const float* __restrict__ X, const float* __restrict__ AW,
                         const float* __restrict__ W,
                         unsigned short* __restrict__ PX, unsigned short* __restrict__ PW) {
  if (blockIdx.x < 512) {
    int gid = blockIdx.x * 256 + threadIdx.x;
    int l   = gid & 63;
    int g   = gid >> 6;                          // 0..2047
    int kk  = g & 255;
    int nt  = g >> 8;
    int col = nt * 16 + (l & 15);
    int k0  = kk * 32 + (l >> 4) * 8;
    unsigned int w[4];
#pragma unroll
    for (int p = 0; p < 4; ++p)
      w[p] = pack2(X[(size_t)(k0 + 2 * p) * FI + col], X[(size_t)(k0 + 2 * p + 1) * FI + col]);
    ((uint4*)PX)[g * 64 + l] = make_uint4(w[0], w[1], w[2], w[3]);
  } else {
    int gid = (blockIdx.x - 512) * 256 + threadIdx.x;
    int l   = gid & 63;
    int g   = gid >> 6;                          // 0..159 (= c*32 + ot*4 + ks)
    int ks  = g & 3;
    int ot  = (g >> 2) & 7;
    int c   = g >> 5;                            // 0..4 ; 4 == W
    const float* base = (c < 4) ? (AW + (size_t)c * FI * FO) : W;
    int col = ot * 16 + (l & 15);
    int k0  = ks * 32 + (l >> 4) * 8;
    unsigned int w[4];
#pragma unroll
    for (int p = 0; p < 4; ++p)
      w[p] = pack2(base[(k0 + 2 * p) * FO + col], base[(k0 + 2 * p + 1) * FO + col]);
    ((uint4*)PW)[g * 64 + l] = make_uint4(w[0], w[1], w[2], w[3]);
  }
}

// ---------------------------------------------------------------------------
// Main (fused, 1 block/CU, 8 waves, LDS-limited to 1 block). R4 staging:
// half = [4ch][32r][256k] bf16 = 64 KB, double-buffered. FIFO-clean pipeline:
//  - COMPUTE has ZERO global loads (B-frags preloaded into Breg in order)
//  - raw barrier drains lgkm only -> A-prefetch loads stay in flight across it
//  - 2-deep A prefetch (pfA/pfB, compile-time parity)
// Epilogue: per-ch relu(AX_c @ adjW_c) + X@W + b, relu, store. No atomics.
// ---------------------------------------------------------------------------
__global__ void __launch_bounds__(512, 2)
gcs_main(const float* __restrict__ adjs, const unsigned short* __restrict__ PX,
         const unsigned short* __restrict__ PW, const float* __restrict__ X,
         const float* __restrict__ b, float* __restrict__ out) {
  const int rt  = blockIdx.x;      // 0..255 row tile
  const int tid = threadIdx.x;
  const int w   = tid >> 6;        // wave 0..7 (owns col-tile w)
  const int l   = tid & 63;
  const int lr  = l & 15;
  const int lk  = l >> 4;

  // buf[p]: channel c at c*16384 + ((r*512 + k*2) ^ ((r&7)<<4))
  __shared__ unsigned short buf[2][NCH * 32 * HK];   // 128 KB

  f32x4  acc[NCH][2] = {};
  f32x4  pfA[16], pfB[16];        // A prefetch, 2-deep, static indices
  bf16x8 Breg[8];                 // B-frags for current half

#define LA(pf, h)                                                              \
  _Pragma("unroll") for (int j = 0; j < 16; ++j) {                             \
    int p = w * 16 + j; int c = p >> 5; int r = p & 31;                        \
    const float* src = adjs + (size_t)c * NN * NN +                            \
        (size_t)(rt * 32 + r) * NN + (size_t)(h) * HK + l * 4;                 \
    pf[j] = __builtin_nontemporal_load((const f32x4*)src);                     \
  }

#define CVT(dst, pf)                                                           \
  _Pragma("unroll") for (int j = 0; j < 16; ++j) {                             \
    int p = w * 16 + j; int c = p >> 5; int r = p & 31;                        \
    unsigned int w0 = pack2(pf[j][0], pf[j][1]);                               \
    unsigned int w1 = pack2(pf[j][2], pf[j][3]);                               \
    int byte = c * 16384 + ((r * 512 + l * 8) ^ ((r & 7) << 4));               \
    *(uint2*)((char*)(dst) + byte) = make_uint2(w0, w1);                       \
  }

#define LB(h)                                                                  \
  _Pragma("unroll") for (int s = 0; s < 8; ++s) {                              \
    Breg[s] = *(const bf16x8*)((const char*)PX +                               \
        ((size_t)(w * 256 + (h) * 8 + s) * 64 + l) * 16);                      \
  }

#define COMP(bufp)                                                             \
  _Pragma("unroll") for (int s = 0; s < 8; ++s) {                              \
    _Pragma("unroll") for (int c = 0; c < NCH; ++c) {                          \
      _Pragma("unroll") for (int m = 0; m < 2; ++m) {                          \
        int r = m * 16 + lr;                                                   \
        int byt = c * 16384 + ((r * 512 + s * 64 + lk * 16) ^ ((r & 7) << 4)); \
        bf16x8 A = __builtin_bit_cast(bf16x8,                                  \
            *(const short8*)((const char*)(bufp) + byt));                      \
        acc[c][m] = mfma16(A, Breg[s], acc[c][m]);                             \
      }                                                                        \
    }                                                                          \
  }

#define BARRIER() asm volatile("s_waitcnt lgkmcnt(0)\n\ts_barrier" ::: "memory")

  // ---- prologue ----
  LA(pfA, 0);
  LA(pfB, 1);
  CVT(buf[0], pfA);     // waits on LA(0) only
  LB(0);
  LA(pfA, 2);
  BARRIER();

  // ---- 16 iterations x 2 halves ----
  for (int hh = 0; hh < 16; ++hh) {
    const int e = 2 * hh, o = 2 * hh + 1;
    COMP(buf[0]);                       // half e, uses Breg=B(e)
    CVT(buf[1], pfB);                   // half o   (waits LA(o))
    LB(o);
    if (hh < 15) LA(pfB, o + 2);
    BARRIER();

    COMP(buf[1]);                       // half o, uses Breg=B(o)
    if (hh < 15) {
      CVT(buf[0], pfA);                 // half e+2 (waits LA(e+2))
      LB(e + 2);
      if (e + 4 < NH) LA(pfA, e + 4);
    }
    BARRIER();
  }

  // ---- epilogue: per channel relu(AX_c @ adjW_c), summed in regs ----
  char* AXs = (char*)buf;               // 8 KB scratch (aliases buf)
  f32x4 osum0 = {}, osum1 = {};
#pragma unroll
  for (int c = 0; c < NCH; ++c) {
    __syncthreads();
#pragma unroll
    for (int m = 0; m < 2; ++m) {
#pragma unroll
      for (int rr = 0; rr < 4; ++rr) {
        int row = m * 16 + lk * 4 + rr;
        int col = w * 16 + lr;
        int byte = (row * 256 + col * 2) ^ ((row & 7) << 4);
        *(unsigned short*)(AXs + byte) = f2bfu(acc[c][m][rr]);
      }
    }
    __syncthreads();
    f32x4 p0 = {}, p1 = {};
#pragma unroll
    for (int ks = 0; ks < 4; ++ks) {
      int kb = ks * 64 + lk * 16;
      int r0 = lr, r1 = 16 + lr;
      int b0 = (r0 * 256 + kb) ^ ((r0 & 7) << 4);
      int b1 = (r1 * 256 + kb) ^ ((r1 & 7) << 4);
      bf16x8 a0 = __builtin_bit_cast(bf16x8, *(const short8*)(AXs + b0));
      bf16x8 a1 = __builtin_bit_cast(bf16x8, *(const short8*)(AXs + b1));
      bf16x8 bw = *(const bf16x8*)((const char*)PW +
          ((size_t)(c * 32 + w * 4 + ks) * 64 + l) * 16);
      p0 = mfma16(a0, bw, p0);
      p1 = mfma16(a1, bw, p1);
    }
#pragma unroll
    for (int rr = 0; rr < 4; ++rr) {
      osum0[rr] += fmaxf(p0[rr], 0.0f);
      osum1[rr] += fmaxf(p1[rr], 0.0f);
    }
  }

  // ---- fused x_part = X@W via MFMA ----
  f32x4 xp0 = {}, xp1 = {};
#pragma unroll
  for (int ks = 0; ks < 4; ++ks) {
    bf16x8 bw = *(const bf16x8*)((const char*)PW +
        ((size_t)(128 + w * 4 + ks) * 64 + l) * 16);
#pragma unroll
    for (int m = 0; m < 2; ++m) {
      int row_g = rt * 32 + m * 16 + lr;
      const float* px = X + (size_t)row_g * FI + ks * 32 + lk * 8;
      f32x4 xa = *(const f32x4*)px;
      f32x4 xb = *(const f32x4*)(px + 4);
      bf16x8 a = cvt8v(xa, xb);
      if (m == 0) xp0 = mfma16(a, bw, xp0);
      else        xp1 = mfma16(a, bw, xp1);
    }
  }

  // ---- total = adj_part + x_part + b ; relu ; store ----
  float bias = b[w * 16 + lr];
#pragma unroll
  for (int m = 0; m < 2; ++m) {
#pragma unroll
    for (int rr = 0; rr < 4; ++rr) {
      int row = rt * 32 + m * 16 + lk * 4 + rr;
      int col = w * 16 + lr;
      float s = (m == 0 ? osum0[rr] : osum1[rr]) +
                (m == 0 ? xp0[rr]   : xp1[rr]) + bias;
      out[(size_t)row * FO + col] = fmaxf(s, 0.0f);
    }
  }
#undef LA
#undef CVT
#undef LB
#undef COMP
#undef BARRIER
}

extern "C" void kernel_launch(void* const* d_in, const int* in_sizes, int n_in,
                              void* d_out, int out_size, void* d_ws, size_t ws_size,
                              hipStream_t stream) {
  const float* X    = (const float*)d_in[0];   // [8192][128]
  const float* adjs = (const float*)d_in[1];   // [4][8192][8192]
  const float* W    = (const float*)d_in[2];   // [128][128]
  const float* AW   = (const float*)d_in[3];   // [4][128][128]
  const float* b    = (const float*)d_in[4];   // [128]
  float* out = (float*)d_out;

  char* ws = (char*)d_ws;
  unsigned short* PX = (unsigned short*)ws;                 // 2 MB
  unsigned short* PW = (unsigned short*)(ws + (2u << 20));  // 160 KB

  hipLaunchKernelGGL(gcs_prep, dim3(552), dim3(256), 0, stream, X, AW, W, PX, PW);
  hipLaunchKernelGGL(gcs_main, dim3(256), dim3(512), 0, stream, adjs, PX, PW, X, b, out);
}

// Round 7
// 185.429 us; speedup vs baseline: 1.3752x; 1.1849x over previous
//
#include <hip/hip_runtime.h>
#include <cstdint>
#include <cstddef>

#define NN 8192
#define FI 128
#define FO 128
#define NCH 4
#define HK 256              // k-floats per half-buffer
#define NH (NN / HK)        // 32 halves

typedef __attribute__((ext_vector_type(8))) __bf16 bf16x8;
typedef __attribute__((ext_vector_type(8))) short short8;
typedef __attribute__((ext_vector_type(4))) float f32x4;

static __device__ __forceinline__ f32x4 mfma16(bf16x8 a, bf16x8 b, f32x4 c) {
  return __builtin_amdgcn_mfma_f32_16x16x32_bf16(a, b, c, 0, 0, 0);
}

static __device__ __forceinline__ unsigned short f2bfu(float f) {
  union { __bf16 h; unsigned short u; } cv;
  cv.h = (__bf16)f;
  return cv.u;
}

static __device__ __forceinline__ unsigned int pack2(float a, float b) {
  return (unsigned int)f2bfu(a) | ((unsigned int)f2bfu(b) << 16);
}

static __device__ __forceinline__ bf16x8 cvt8v(f32x4 a, f32x4 b) {
  bf16x8 v;
  v[0] = (__bf16)a[0]; v[1] = (__bf16)a[1]; v[2] = (__bf16)a[2]; v[3] = (__bf16)a[3];
  v[4] = (__bf16)b[0]; v[5] = (__bf16)b[1]; v[6] = (__bf16)b[2]; v[7] = (__bf16)b[3];
  return v;
}

// ---------------------------------------------------------------------------
// Prep: blocks 0..511 pack X -> PX (B-frag order); blocks 512..551 pack the
// 5 weight matrices (adj_W c=0..3, W as c=4) -> PW.
// B-frag: frag g, lane l holds M[kk*32 + (l>>4)*8 + j][nt*16 + (l&15)].
// ---------------------------------------------------------------------------
__global__ void gcs_prep(const float* __restrict__ X, const float* __restrict__ AW,
                         const float* __restrict__ W,
                         unsigned short* __restrict__ PX, unsigned short* __restrict__ PW) {
  if (blockIdx.x < 512) {
    int gid = blockIdx.x * 256 + threadIdx.x;
    int l   = gid & 63;
    int g   = gid >> 6;                          // 0..2047
    int kk  = g & 255;
    int nt  = g >> 8;
    int col = nt * 16 + (l & 15);
    int k0  = kk * 32 + (l >> 4) * 8;
    unsigned int w[4];
#pragma unroll
    for (int p = 0; p < 4; ++p)
      w[p] = pack2(X[(size_t)(k0 + 2 * p) * FI + col], X[(size_t)(k0 + 2 * p + 1) * FI + col]);
    ((uint4*)PX)[g * 64 + l] = make_uint4(w[0], w[1], w[2], w[3]);
  } else {
    int gid = (blockIdx.x - 512) * 256 + threadIdx.x;
    int l   = gid & 63;
    int g   = gid >> 6;                          // 0..159 (= c*32 + ot*4 + ks)
    int ks  = g & 3;
    int ot  = (g >> 2) & 7;
    int c   = g >> 5;                            // 0..4 ; 4 == W
    const float* base = (c < 4) ? (AW + (size_t)c * FI * FO) : W;
    int col = ot * 16 + (l & 15);
    int k0  = ks * 32 + (l >> 4) * 8;
    unsigned int w[4];
#pragma unroll
    for (int p = 0; p < 4; ++p)
      w[p] = pack2(base[(k0 + 2 * p) * FO + col], base[(k0 + 2 * p + 1) * FO + col]);
    ((uint4*)PW)[g * 64 + l] = make_uint4(w[0], w[1], w[2], w[3]);
  }
}

// ---------------------------------------------------------------------------
// Main (fused, 1 block/CU, 8 waves). R4 staging geometry (half = [4c][32r][256k]
// bf16 = 64 KB, 1 KB/row bursts), R6 barrier discipline, R4 register budget:
//  - single pf[16] (64 VGPR), Breg[8] (32), acc (32) -> no spill
//  - COMPUTE consumes only Breg/LDS: vmcnt wait leaves next A-loads in flight
//  - lgkm-only barrier -> A-loads live across it; HBM idles only during CVT
// Phase: COMP(h) | CVT(h+1) LB(h+1) LA(h+2) | barrier
// ---------------------------------------------------------------------------
__global__ void __launch_bounds__(512, 2)
gcs_main(const float* __restrict__ adjs, const unsigned short* __restrict__ PX,
         const unsigned short* __restrict__ PW, const float* __restrict__ X,
         const float* __restrict__ b, float* __restrict__ out) {
  const int rt  = blockIdx.x;      // 0..255 row tile
  const int tid = threadIdx.x;
  const int w   = tid >> 6;        // wave 0..7 (owns col-tile w)
  const int l   = tid & 63;
  const int lr  = l & 15;
  const int lk  = l >> 4;

  // buf[p]: channel c at c*16384 + ((r*512 + k*2) ^ ((r&7)<<4))
  __shared__ unsigned short buf[2][NCH * 32 * HK];   // 128 KB

  f32x4  acc[NCH][2] = {};
  f32x4  pf[16];                  // 1-deep A prefetch (64 VGPR)
  bf16x8 Breg[8];                 // B-frags for current half (32 VGPR)

#define LA(h)                                                                  \
  _Pragma("unroll") for (int j = 0; j < 16; ++j) {                             \
    int p = w * 16 + j; int c = p >> 5; int r = p & 31;                        \
    const float* src = adjs + (size_t)c * NN * NN +                            \
        (size_t)(rt * 32 + r) * NN + (size_t)(h) * HK + l * 4;                 \
    pf[j] = __builtin_nontemporal_load((const f32x4*)src);                     \
  }

#define CVT(dst)                                                               \
  _Pragma("unroll") for (int j = 0; j < 16; ++j) {                             \
    int p = w * 16 + j; int c = p >> 5; int r = p & 31;                        \
    unsigned int w0 = pack2(pf[j][0], pf[j][1]);                               \
    unsigned int w1 = pack2(pf[j][2], pf[j][3]);                               \
    int byte = c * 16384 + ((r * 512 + l * 8) ^ ((r & 7) << 4));               \
    *(uint2*)((char*)(dst) + byte) = make_uint2(w0, w1);                       \
  }

#define LB(h)                                                                  \
  _Pragma("unroll") for (int s = 0; s < 8; ++s) {                              \
    Breg[s] = *(const bf16x8*)((const char*)PX +                               \
        ((size_t)(w * 256 + (h) * 8 + s) * 64 + l) * 16);                      \
  }

#define COMP(bufp)                                                             \
  _Pragma("unroll") for (int s = 0; s < 8; ++s) {                              \
    _Pragma("unroll") for (int c = 0; c < NCH; ++c) {                          \
      _Pragma("unroll") for (int m = 0; m < 2; ++m) {                          \
        int r = m * 16 + lr;                                                   \
        int byt = c * 16384 + ((r * 512 + s * 64 + lk * 16) ^ ((r & 7) << 4)); \
        bf16x8 A = __builtin_bit_cast(bf16x8,                                  \
            *(const short8*)((const char*)(bufp) + byt));                      \
        acc[c][m] = mfma16(A, Breg[s], acc[c][m]);                             \
      }                                                                        \
    }                                                                          \
  }

#define BARRIER() asm volatile("s_waitcnt lgkmcnt(0)\n\ts_barrier" ::: "memory")

  // ---- prologue: stage half 0, preload B(0), issue A(1) ----
  LA(0);
  CVT(buf[0]);          // drains LA(0)
  LB(0);                // B(0) -> Breg
  LA(1);                // A(1) in flight across barrier
  BARRIER();

  // ---- 32 halves; one lgkm-barrier each; A-loads live through COMP ----
  for (int h = 0; h < NH; ++h) {
    COMP(buf[h & 1]);               // waits vmcnt(16): Breg(h) only; A(h+1) stays in flight
    if (h + 1 < NH) {
      CVT(buf[(h + 1) & 1]);        // drains A(h+1)
      LB(h + 1);                    // B(h+1) (issued BEFORE next A batch)
      if (h + 2 < NH) LA(h + 2);    // A(h+2) in flight across barrier + next COMP
    }
    BARRIER();
  }

  // ---- epilogue: per channel relu(AX_c @ adjW_c), summed in regs ----
  char* AXs = (char*)buf;               // 8 KB scratch (aliases buf)
  f32x4 osum0 = {}, osum1 = {};
#pragma unroll
  for (int c = 0; c < NCH; ++c) {
    __syncthreads();
#pragma unroll
    for (int m = 0; m < 2; ++m) {
#pragma unroll
      for (int rr = 0; rr < 4; ++rr) {
        int row = m * 16 + lk * 4 + rr;
        int col = w * 16 + lr;
        int byte = (row * 256 + col * 2) ^ ((row & 7) << 4);
        *(unsigned short*)(AXs + byte) = f2bfu(acc[c][m][rr]);
      }
    }
    __syncthreads();
    f32x4 p0 = {}, p1 = {};
#pragma unroll
    for (int ks = 0; ks < 4; ++ks) {
      int kb = ks * 64 + lk * 16;
      int r0 = lr, r1 = 16 + lr;
      int b0 = (r0 * 256 + kb) ^ ((r0 & 7) << 4);
      int b1 = (r1 * 256 + kb) ^ ((r1 & 7) << 4);
      bf16x8 a0 = __builtin_bit_cast(bf16x8, *(const short8*)(AXs + b0));
      bf16x8 a1 = __builtin_bit_cast(bf16x8, *(const short8*)(AXs + b1));
      bf16x8 bw = *(const bf16x8*)((const char*)PW +
          ((size_t)(c * 32 + w * 4 + ks) * 64 + l) * 16);
      p0 = mfma16(a0, bw, p0);
      p1 = mfma16(a1, bw, p1);
    }
#pragma unroll
    for (int rr = 0; rr < 4; ++rr) {
      osum0[rr] += fmaxf(p0[rr], 0.0f);
      osum1[rr] += fmaxf(p1[rr], 0.0f);
    }
  }

  // ---- fused x_part = X@W via MFMA ----
  f32x4 xp0 = {}, xp1 = {};
#pragma unroll
  for (int ks = 0; ks < 4; ++ks) {
    bf16x8 bw = *(const bf16x8*)((const char*)PW +
        ((size_t)(128 + w * 4 + ks) * 64 + l) * 16);
#pragma unroll
    for (int m = 0; m < 2; ++m) {
      int row_g = rt * 32 + m * 16 + lr;
      const float* px = X + (size_t)row_g * FI + ks * 32 + lk * 8;
      f32x4 xa = *(const f32x4*)px;
      f32x4 xb = *(const f32x4*)(px + 4);
      bf16x8 a = cvt8v(xa, xb);
      if (m == 0) xp0 = mfma16(a, bw, xp0);
      else        xp1 = mfma16(a, bw, xp1);
    }
  }

  // ---- total = adj_part + x_part + b ; relu ; store ----
  float bias = b[w * 16 + lr];
#pragma unroll
  for (int m = 0; m < 2; ++m) {
#pragma unroll
    for (int rr = 0; rr < 4; ++rr) {
      int row = rt * 32 + m * 16 + lk * 4 + rr;
      int col = w * 16 + lr;
      float s = (m == 0 ? osum0[rr] : osum1[rr]) +
                (m == 0 ? xp0[rr]   : xp1[rr]) + bias;
      out[(size_t)row * FO + col] = fmaxf(s, 0.0f);
    }
  }
#undef LA
#undef CVT
#undef LB
#undef COMP
#undef BARRIER
}

extern "C" void kernel_launch(void* const* d_in, const int* in_sizes, int n_in,
                              void* d_out, int out_size, void* d_ws, size_t ws_size,
                              hipStream_t stream) {
  const float* X    = (const float*)d_in[0];   // [8192][128]
  const float* adjs = (const float*)d_in[1];   // [4][8192][8192]
  const float* W    = (const float*)d_in[2];   // [128][128]
  const float* AW   = (const float*)d_in[3];   // [4][128][128]
  const float* b    = (const float*)d_in[4];   // [128]
  float* out = (float*)d_out;

  char* ws = (char*)d_ws;
  unsigned short* PX = (unsigned short*)ws;                 // 2 MB
  unsigned short* PW = (unsigned short*)(ws + (2u << 20));  // 160 KB

  hipLaunchKernelGGL(gcs_prep, dim3(552), dim3(256), 0, stream, X, AW, W, PX, PW);
  hipLaunchKernelGGL(gcs_main, dim3(256), dim3(512), 0, stream, adjs, PX, PW, X, b, out);
}